// Round 8
// baseline (137.751 us; speedup 1.0000x reference)
//
#include <hip/hip_runtime.h>

// Head_enc: out = softmax((xWq)(xWk)^T * C^-0.5) (xWv)
// B=8 T=2048 C=768 H=64. bf16 MFMA 16x16x32, fp32 accum.
// 4 kernels: wconv -> proj -> attn (no-max flash, s/8 partials) -> comb.
// attn v2: K/V fragments direct from global (L2-resident, XCD-affine),
// S^T via operand swap -> P transform is ds_write_b64 + ds_read_b128 only,
// 32 q-rows/wave, zero __syncthreads. (Round-7 analysis: old attn was
// LDS-port-bound, ~280 LDS cyc vs 86 MFMA cyc per wave-iter.)
// ws (256MB proven): kg[2M] | qg[2M@2M] | vt[2M@4M] | wt[288K@6M]
//                    | part[16M@7M] | lsum[512K@23M]

typedef __attribute__((ext_vector_type(4))) float f32x4;
typedef __attribute__((ext_vector_type(4))) unsigned short u16x4;
typedef __attribute__((ext_vector_type(8))) unsigned short u16x8;
typedef __attribute__((ext_vector_type(8))) __bf16 bf16x8;
typedef __attribute__((ext_vector_type(8))) _Float16 f16x8;

#define LDR 72   // LDS row stride (ushorts); 144 B = 16B-aligned rows
#define LDT 40   // LDS row stride for 32-wide vt transpose
#define KSCALE (0.03608439182435161f * 1.4426950408889634f)  // C^-0.5 * log2(e)
#define PBIAS 4.0f

__device__ __forceinline__ unsigned short f2bf(float f) {
  unsigned int u = __float_as_uint(f);
  u += 0x7FFFu + ((u >> 16) & 1u);  // RNE
  return (unsigned short)(u >> 16);
}
__device__ __forceinline__ unsigned short hi16(float f) {  // truncate to bf16
  return (unsigned short)(__float_as_uint(f) >> 16);
}
__device__ __forceinline__ f32x4 mfma_bf16(u16x8 a, u16x8 b, f32x4 c) {
  return __builtin_amdgcn_mfma_f32_16x16x32_bf16(
      __builtin_bit_cast(bf16x8, a), __builtin_bit_cast(bf16x8, b), c, 0, 0, 0);
}
__device__ __forceinline__ void cp32B(unsigned short* dst, const unsigned short* src) {
  *(u16x8*)dst = *(const u16x8*)src;
  *(u16x8*)(dst + 8) = *(const u16x8*)(src + 8);
}

// ---- kernel 1: W[768,64] fp32 -> Wt[w][n=64][k=768] bf16, LDS transpose ----
__global__ __launch_bounds__(256) void wconv_k(const float* __restrict__ Wk,
                                               const float* __restrict__ Wq,
                                               const float* __restrict__ Wv,
                                               unsigned short* __restrict__ wt) {
  __shared__ unsigned short tr[64 * LDR];
  const int w = blockIdx.x / 12;
  const int kt = blockIdx.x - w * 12;
  const float* W = (w == 0) ? Wk : ((w == 1) ? Wq : Wv);
  const int tid = threadIdx.x;
  const int kr = tid >> 2;
  const int n0 = (tid & 3) * 16;
  const f32x4* src = (const f32x4*)(W + (size_t)(kt * 64 + kr) * 64 + n0);
  f32x4 a0 = src[0], a1 = src[1], a2 = src[2], a3 = src[3];
#pragma unroll
  for (int j = 0; j < 4; ++j) {
    tr[(n0 + j) * LDR + kr] = f2bf(a0[j]);
    tr[(n0 + 4 + j) * LDR + kr] = f2bf(a1[j]);
    tr[(n0 + 8 + j) * LDR + kr] = f2bf(a2[j]);
    tr[(n0 + 12 + j) * LDR + kr] = f2bf(a3[j]);
  }
  __syncthreads();
  const int n = tid >> 2, kc = (tid & 3) * 16;
  cp32B(&wt[(size_t)(w * 64 + n) * 768 + kt * 64 + kc], &tr[n * LDR + kc]);
}

// ---- kernel 2: fused QKV proj. M-tile 32, grid 512 (2 blk/CU). ----
// q is pre-scaled by KSCALE so attn's exp2 arg is (score - PBIAS) directly.
__global__ __launch_bounds__(256) void proj_k(const float* __restrict__ x,
                                              const unsigned short* __restrict__ wt,
                                              unsigned short* __restrict__ kg,
                                              unsigned short* __restrict__ qg,
                                              unsigned short* __restrict__ vt) {
  __shared__ unsigned short x_s[32 * LDR];
  __shared__ unsigned short w_s[192 * LDR];
  __shared__ unsigned short vt_s[64 * LDT];
  const int tid = threadIdx.x;
  const int wv = tid >> 6, lane = tid & 63, c = lane & 15, quad = lane >> 4;
  const int m0 = blockIdx.x * 32;
  const int rowg = wv & 1;
  const int nfb = (wv >> 1) * 6;
  const int srow = tid >> 3;
  const int sc8 = (tid & 7) * 8;

  f32x4 acc[6];
#pragma unroll
  for (int i = 0; i < 6; ++i) acc[i] = f32x4{0.f, 0.f, 0.f, 0.f};

  f32x4 xf0, xf1;
  u16x8 wf[6];
  {
    const f32x4* s = (const f32x4*)(x + (size_t)(m0 + srow) * 768 + sc8);
    xf0 = s[0]; xf1 = s[1];
  }
#pragma unroll
  for (int i = 0; i < 6; ++i)
    wf[i] = *(const u16x8*)&wt[(size_t)(srow + 32 * i) * 768 + sc8];

  for (int kc = 0; kc < 768; kc += 64) {
    {
      u16x8 u;
#pragma unroll
      for (int j = 0; j < 4; ++j) { u[j] = f2bf(xf0[j]); u[4 + j] = f2bf(xf1[j]); }
      *(u16x8*)&x_s[srow * LDR + sc8] = u;
    }
#pragma unroll
    for (int i = 0; i < 6; ++i)
      *(u16x8*)&w_s[(srow + 32 * i) * LDR + sc8] = wf[i];
    __syncthreads();
    if (kc + 64 < 768) {  // prefetch next tiles over the MFMA phase
      const f32x4* s = (const f32x4*)(x + (size_t)(m0 + srow) * 768 + kc + 64 + sc8);
      xf0 = s[0]; xf1 = s[1];
#pragma unroll
      for (int i = 0; i < 6; ++i)
        wf[i] = *(const u16x8*)&wt[(size_t)(srow + 32 * i) * 768 + kc + 64 + sc8];
    }
#pragma unroll
    for (int k32 = 0; k32 < 2; ++k32) {
      u16x8 a = *(const u16x8*)&x_s[(rowg * 16 + c) * LDR + k32 * 32 + quad * 8];
#pragma unroll
      for (int j = 0; j < 6; ++j) {
        u16x8 b = *(const u16x8*)&w_s[((nfb + j) * 16 + c) * LDR + k32 * 32 + quad * 8];
        acc[j] = mfma_bf16(a, b, acc[j]);
      }
    }
    __syncthreads();
  }
  const int r0 = rowg * 16 + quad * 4;
#pragma unroll
  for (int j = 0; j < 6; ++j) {
    const int nf = nfb + j;  // wave-uniform
    if (nf < 4) {
#pragma unroll
      for (int r = 0; r < 4; ++r)
        kg[(size_t)(m0 + r0 + r) * 64 + nf * 16 + c] = f2bf(acc[j][r]);
    } else if (nf < 8) {
#pragma unroll
      for (int r = 0; r < 4; ++r)
        qg[(size_t)(m0 + r0 + r) * 64 + (nf - 4) * 16 + c] = f2bf(acc[j][r] * KSCALE);
    } else {
#pragma unroll
      for (int r = 0; r < 4; ++r)
        vt_s[((nf - 8) * 16 + c) * LDT + r0 + r] = f2bf(acc[j][r]);
    }
  }
  __syncthreads();
  {
    const int h = tid >> 2, c8 = (tid & 3) * 8;
    const int b = m0 >> 11, tb = m0 & 2047;
    *(u16x8*)(vt + (size_t)b * 131072 + (size_t)h * 2048 + tb + c8) =
        *(const u16x8*)&vt_s[h * LDT + c8];
  }
}

// ---- kernel 3: flash partial v2. grid (bq=8, qt=16, sc=8), 128 q/block. ----
// No barriers; K/V B-frags direct from global (L2); P via b64/b128 LDS only.
__global__ __launch_bounds__(256, 3) void attn_k(const unsigned short* __restrict__ qg,
                                                 const unsigned short* __restrict__ kg,
                                                 const unsigned short* __restrict__ vt,
                                                 _Float16* __restrict__ part,
                                                 float* __restrict__ lsum) {
  __shared__ unsigned short p_s[128 * LDR];  // per-wave 32-row slices, [q][s]
  const int tid = threadIdx.x;
  const int wv = tid >> 6, lane = tid & 63, c = lane & 15, quad = lane >> 4;
  const int bq = blockIdx.x;   // %8 == XCD affinity for K/V L2
  const int qt = blockIdx.y;
  const int sc = blockIdx.z;
  const int q0 = qt * 128 + wv * 32;
  const int s_beg = sc << 8;

  const unsigned short* kbase = kg + (size_t)bq * 131072;
  const unsigned short* vbase = vt + (size_t)bq * 131072;

  u16x8 aq[2][2];  // Q as B-operand; bytes identical to A-layout load
#pragma unroll
  for (int m = 0; m < 2; ++m)
#pragma unroll
    for (int k32 = 0; k32 < 2; ++k32)
      aq[m][k32] = *(const u16x8*)(qg + (size_t)(bq * 2048 + q0 + m * 16 + c) * 64 +
                                   k32 * 32 + quad * 8);

  u16x8 ones;
#pragma unroll
  for (int j = 0; j < 8; ++j) ones[j] = 0x3F80;  // bf16 1.0

  f32x4 o_acc[2][4];
  f32x4 l_acc[2];
#pragma unroll
  for (int m = 0; m < 2; ++m) {
#pragma unroll
    for (int hf = 0; hf < 4; ++hf) o_acc[m][hf] = f32x4{0.f, 0.f, 0.f, 0.f};
    l_acc[m] = f32x4{0.f, 0.f, 0.f, 0.f};
  }
  const int prow0 = wv * 32;  // this wave's p_s base row

  for (int s0 = s_beg; s0 < s_beg + 256; s0 += 64) {
    // K frags from global: K[s = s0+nf*16+c][ch], 16B/lane, L2-hit
    u16x8 kf[2][4];
#pragma unroll
    for (int k32 = 0; k32 < 2; ++k32)
#pragma unroll
      for (int nf = 0; nf < 4; ++nf)
        kf[k32][nf] = *(const u16x8*)(kbase + (size_t)(s0 + nf * 16 + c) * 64 +
                                      k32 * 32 + quad * 8);
    // S^T tiles: st[m][nf] row = s-local(quad*4+r), col = q-local(c)
    f32x4 st[2][4];
#pragma unroll
    for (int m = 0; m < 2; ++m)
#pragma unroll
      for (int nf = 0; nf < 4; ++nf) st[m][nf] = f32x4{0.f, 0.f, 0.f, 0.f};
#pragma unroll
    for (int k32 = 0; k32 < 2; ++k32)
#pragma unroll
      for (int m = 0; m < 2; ++m)
#pragma unroll
        for (int nf = 0; nf < 4; ++nf)
          st[m][nf] = mfma_bf16(kf[k32][nf], aq[m][k32], st[m][nf]);
    // p = exp2(score-4) trunc bf16; S^T layout -> 4 consecutive s per lane
    // -> vector ds_write_b64 into p_s[q][s]
#pragma unroll
    for (int m = 0; m < 2; ++m)
#pragma unroll
      for (int nf = 0; nf < 4; ++nf) {
        u16x4 w;
#pragma unroll
        for (int r = 0; r < 4; ++r)
          w[r] = hi16(__builtin_amdgcn_exp2f(st[m][nf][r] - PBIAS));
        *(u16x4*)&p_s[(prow0 + m * 16 + c) * LDR + nf * 16 + quad * 4] = w;
      }
    // V frags from global: V^T[h = hf*16+c][s], 16B/lane, L2-hit
    u16x8 vf[2][4];
#pragma unroll
    for (int s32 = 0; s32 < 2; ++s32)
#pragma unroll
      for (int hf = 0; hf < 4; ++hf)
        vf[s32][hf] = *(const u16x8*)(vbase + (size_t)(hf * 16 + c) * 2048 + s0 +
                                      s32 * 32 + quad * 8);
    asm volatile("s_waitcnt lgkmcnt(0)" ::: "memory");  // drain P writes (intra-wave)
#pragma unroll
    for (int m = 0; m < 2; ++m)
#pragma unroll
      for (int s32 = 0; s32 < 2; ++s32) {
        u16x8 ap = *(const u16x8*)&p_s[(prow0 + m * 16 + c) * LDR + s32 * 32 + quad * 8];
#pragma unroll
        for (int hf = 0; hf < 4; ++hf)
          o_acc[m][hf] = mfma_bf16(ap, vf[s32][hf], o_acc[m][hf]);
        l_acc[m] = mfma_bf16(ap, ones, l_acc[m]);  // row-sum of P via MFMA
      }
  }
  const int pbase = (bq * 16 + qt) * 8 + sc;
  _Float16* po = part + (size_t)pbase * 8192;
#pragma unroll
  for (int m = 0; m < 2; ++m)
#pragma unroll
    for (int hf = 0; hf < 4; ++hf)
#pragma unroll
      for (int r = 0; r < 4; ++r)
        po[(wv * 32 + m * 16 + quad * 4 + r) * 64 + hf * 16 + c] =
            (_Float16)o_acc[m][hf][r];
  if (c == 0) {
#pragma unroll
    for (int m = 0; m < 2; ++m)
#pragma unroll
      for (int r = 0; r < 4; ++r)
        lsum[pbase * 128 + wv * 32 + m * 16 + quad * 4 + r] = l_acc[m][r];
  }
}

// ---- kernel 4: combine = plain sum of 8 partials, divide by summed l ----
__global__ __launch_bounds__(256) void comb_k(const _Float16* __restrict__ part,
                                              const float* __restrict__ lsum,
                                              float* __restrict__ out) {
  const int bq = blockIdx.x, y = blockIdx.y;  // grid (8, 64)
  const int qglob = y * 32 + (threadIdx.x >> 3);
  const int tile = qglob >> 7;       // 128-row partial tile
  const int row = qglob & 127;
  const int h0 = (threadIdx.x & 7) * 8;
  const int base = (bq * 16 + tile) * 8;
  float acc[8];
#pragma unroll
  for (int j = 0; j < 8; ++j) acc[j] = 0.f;
  float l = 0.f;
#pragma unroll
  for (int c8 = 0; c8 < 8; ++c8) {
    l += lsum[(base + c8) * 128 + row];
    f16x8 p = *(const f16x8*)(part + (size_t)(base + c8) * 8192 + row * 64 + h0);
#pragma unroll
    for (int j = 0; j < 8; ++j) acc[j] += (float)p[j];
  }
  const float inv = 1.0f / l;
  float* op = out + (size_t)(bq * 2048 + qglob) * 64 + h0;
#pragma unroll
  for (int j = 0; j < 8; ++j) op[j] = acc[j] * inv;
}

extern "C" void kernel_launch(void* const* d_in, const int* in_sizes, int n_in,
                              void* d_out, int out_size, void* d_ws, size_t ws_size,
                              hipStream_t stream) {
  const float* x = (const float*)d_in[0];
  const float* Wk = (const float*)d_in[1];
  const float* Wq = (const float*)d_in[2];
  const float* Wv = (const float*)d_in[3];
  char* ws = (char*)d_ws;
  unsigned short* kg = (unsigned short*)(ws);
  unsigned short* qg = (unsigned short*)(ws + (size_t)(2 << 20));
  unsigned short* vt = (unsigned short*)(ws + (size_t)(4 << 20));
  unsigned short* wt = (unsigned short*)(ws + (size_t)(6 << 20));
  _Float16* part = (_Float16*)(ws + (size_t)(7 << 20));    // 16 MB
  float* lsum = (float*)(ws + (size_t)(23 << 20));         // 512 KB
  float* out = (float*)d_out;

  hipLaunchKernelGGL(wconv_k, dim3(36), dim3(256), 0, stream, Wk, Wq, Wv, wt);
  hipLaunchKernelGGL(proj_k, dim3(512), dim3(256), 0, stream, x, wt, kg, qg, vt);
  hipLaunchKernelGGL(attn_k, dim3(8, 16, 8), dim3(256), 0, stream, qg, kg, vt, part, lsum);
  hipLaunchKernelGGL(comb_k, dim3(8, 64), dim3(256), 0, stream, part, lsum, out);
}